// Round 4
// baseline (202.872 us; speedup 1.0000x reference)
//
#include <hip/hip_runtime.h>
#include <hip/hip_cooperative_groups.h>
#include <hip/hip_bf16.h>
#include <math.h>

#define S_LEN   4096
#define HID     2048
#define NB      8
#define SC      128           // s-chunks: one block per 32 rows
#define S_PER   (S_LEN / SC)  // 32 rows per chunk
#define R       16            // TOTAL_RANK
#define AD      32            // ADAPT_DIM

typedef float f4 __attribute__((ext_vector_type(4)));

namespace cg = cooperative_groups;

// One cooperative kernel: 1024 blocks x 256 threads (4 blocks/CU resident).
// Phase 1: mean-pool 32 rows + W1 projection -> xpart (32 floats/block).
// grid.sync()
// Phase 2: per-block redundant controller (identical mask per batch) +
//          masked FWHT-16 over this block's 32 rows of rank_activations.
__global__ __launch_bounds__(256, 4)
void fused_all(const float* __restrict__ hs,
               const float* __restrict__ W1,
               const float* __restrict__ b1,
               const float* __restrict__ gamma,
               const float* __restrict__ beta,
               const float* __restrict__ W2,
               const float* __restrict__ b2v,
               const float* __restrict__ mlog,
               const float* __restrict__ rsc,
               const float* __restrict__ ra,
               float* __restrict__ xpart,
               float* __restrict__ out) {
    __shared__ float hsum[HID];        // 8 KB
    __shared__ float gp[8][AD];        // reused: cpart (ph1), xp (ph2)
    __shared__ float xv[AD];
    __shared__ float xg[AD];
    __shared__ float comb[R];
    __shared__ float ms[R];

    int t   = threadIdx.x;             // 0..255
    int blk = blockIdx.x;              // 0..1023
    int b   = blk >> 7;                // batch (128 blocks per batch)

    // ---------------- Phase 1: pool + project ----------------
    {
        int sc = blk & (SC - 1);
        const float* base = hs + ((size_t)b * S_LEN + (size_t)sc * S_PER) * HID;
        const f4* p0 = (const f4*)(base + t * 4);
        const f4* p1 = (const f4*)(base + 1024 + t * 4);
        f4 a0 = (f4)(0.f);
        f4 a1 = (f4)(0.f);
#pragma unroll 8
        for (int s = 0; s < S_PER; ++s) {
            f4 v0 = __builtin_nontemporal_load(p0 + (size_t)s * (HID / 4));
            f4 v1 = __builtin_nontemporal_load(p1 + (size_t)s * (HID / 4));
            a0 += v0;
            a1 += v1;
        }
        *(f4*)&hsum[t * 4]        = a0;
        *(f4*)&hsum[1024 + t * 4] = a1;
        __syncthreads();

        // c[j] = sum_h hsum[h]*W1[h][j]; 8 groups of 32 lanes
        int j = t & 31, g = t >> 5;
        const float* w = W1 + (size_t)(g * 256) * AD + j;
        float c = 0.f;
#pragma unroll 4
        for (int k = 0; k < 256; ++k)
            c += hsum[g * 256 + k] * w[(size_t)k * AD];
        gp[g][j] = c;
        __syncthreads();

        if (t < AD) {
            float s = 0.f;
#pragma unroll
            for (int gg = 0; gg < 8; ++gg) s += gp[gg][t];
            xpart[((size_t)blk) * AD + t] = s;
        }
    }

    cg::this_grid().sync();

    // ---------------- Phase 2: controller (redundant) ----------------
    {
        int j = t & 31, g = t >> 5;    // 8 groups of 32
        const float* xb = xpart + (size_t)b * SC * AD;
        float s = 0.f;
#pragma unroll 4
        for (int r = 0; r < 16; ++r)
            s += xb[(size_t)(g * 16 + r) * AD + j];
        gp[g][j] = s;
        __syncthreads();

        if (t < AD) {
            float x = 0.f;
#pragma unroll
            for (int gg = 0; gg < 8; ++gg) x += gp[gg][t];
            xv[t] = x * (1.0f / (float)S_LEN) + b1[t];
        }
        __syncthreads();

        if (t < AD) {
            float mu = 0.f;
#pragma unroll
            for (int k = 0; k < AD; ++k) mu += xv[k];
            mu *= (1.0f / AD);
            float var = 0.f;
#pragma unroll
            for (int k = 0; k < AD; ++k) { float d = xv[k] - mu; var += d * d; }
            var *= (1.0f / AD);
            float x = (xv[t] - mu) * rsqrtf(var + 1e-5f) * gamma[t] + beta[t];
            xg[t] = 0.5f * x * (1.0f + erff(x * 0.70710678118654752f)); // exact GELU
        }
        __syncthreads();

        if (t < R) {
            float lg = b2v[t];
#pragma unroll
            for (int k = 0; k < AD; ++k) lg += xg[k] * W2[(size_t)k * R + t];
            comb[t] = lg + mlog[t];
        }
        __syncthreads();

        if (t < R) {
            float v = comb[t];
            int cnt = 0;
#pragma unroll
            for (int k = 0; k < R; ++k)
                cnt += (comb[k] > v) || (comb[k] == v && k < t);
            ms[t] = (cnt < 8) ? rsc[t] : 0.f;
        }
        __syncthreads();
    }

    // ---------------- Phase 2b: masked scale + FWHT-16 ----------------
    // 32 rows per block; threads 0..31 each own one full row.
    if (t < 32) {
        size_t row = (size_t)blk * 32 + t;
        const f4* src = (const f4*)(ra + row * R);
        float a[R];
#pragma unroll
        for (int i = 0; i < 4; ++i) {
            f4 v = __builtin_nontemporal_load(src + i);
            a[4 * i + 0] = v.x; a[4 * i + 1] = v.y;
            a[4 * i + 2] = v.z; a[4 * i + 3] = v.w;
        }
#pragma unroll
        for (int r = 0; r < R; ++r) a[r] *= ms[r];

        // FWHT-16 (Sylvester); recursive /sqrt(n) => total 1/32
#pragma unroll
        for (int hstep = 1; hstep < R; hstep <<= 1) {
#pragma unroll
            for (int i = 0; i < R; ++i) {
                if ((i & hstep) == 0) {
                    float u = a[i], v = a[i | hstep];
                    a[i] = u + v; a[i | hstep] = u - v;
                }
            }
        }

        f4* dst = (f4*)(out + row * R);
#pragma unroll
        for (int i = 0; i < 4; ++i) {
            f4 v;
            v.x = a[4 * i + 0] * 0.03125f; v.y = a[4 * i + 1] * 0.03125f;
            v.z = a[4 * i + 2] * 0.03125f; v.w = a[4 * i + 3] * 0.03125f;
            __builtin_nontemporal_store(v, dst + i);
        }
    }
}

extern "C" void kernel_launch(void* const* d_in, const int* in_sizes, int n_in,
                              void* d_out, int out_size, void* d_ws, size_t ws_size,
                              hipStream_t stream) {
    const float* hs    = (const float*)d_in[0];  // (8,4096,2048)
    const float* ra    = (const float*)d_in[1];  // (8,4096,16)
    const float* W1    = (const float*)d_in[2];  // (2048,32)
    const float* b1    = (const float*)d_in[3];  // (32)
    const float* gamma = (const float*)d_in[4];  // (32)
    const float* beta  = (const float*)d_in[5];  // (32)
    const float* W2    = (const float*)d_in[6];  // (32,16)
    const float* b2v   = (const float*)d_in[7];  // (16)
    const float* mlog  = (const float*)d_in[8];  // (16)
    const float* rsc   = (const float*)d_in[9];  // (16)
    float* out   = (float*)d_out;
    float* xpart = (float*)d_ws;                 // 1024*32 f32 = 128 KB

    void* args[] = {
        (void*)&hs, (void*)&W1, (void*)&b1, (void*)&gamma, (void*)&beta,
        (void*)&W2, (void*)&b2v, (void*)&mlog, (void*)&rsc, (void*)&ra,
        (void*)&xpart, (void*)&out
    };
    hipLaunchCooperativeKernel((void*)fused_all, dim3(NB * SC), dim3(256),
                               args, 0, stream);
}

// Round 5
// 63.884 us; speedup vs baseline: 3.1756x; 3.1756x over previous
//
#include <hip/hip_runtime.h>
#include <hip/hip_bf16.h>
#include <math.h>

#define S_LEN   4096
#define HID     2048
#define NB      8
#define SC      256           // s-chunks: one block per 16 rows
#define S_PER   (S_LEN / SC)  // 16 rows per block
#define R       16            // TOTAL_RANK
#define AD      32            // ADAPT_DIM

typedef float f4 __attribute__((ext_vector_type(4)));

// ---------------- Kernel 1: fused mean-pool + W1 projection ----------------
// grid (256 sc, 8 b), block 256 -> 2048 blocks = 8/CU, 32 waves/CU (full).
// Each block streams 16 full rows (128 KB), reduces to a 2048-float h-sum in
// LDS, projects onto W1 (L2-resident), writes a 32-float partial x row.
__global__ __launch_bounds__(256)
void pool_proj(const float* __restrict__ hs,
               const float* __restrict__ W1,
               float* __restrict__ xpart) {
    __shared__ float hsum[HID];        // 8 KB
    __shared__ float cpart[8][AD];     // 1 KB
    int t  = threadIdx.x;              // 0..255
    int sc = blockIdx.x;               // 0..255
    int b  = blockIdx.y;               // 0..7

    const float* base = hs + ((size_t)b * S_LEN + (size_t)sc * S_PER) * HID;
    const f4* p0 = (const f4*)(base + t * 4);          // cols [t*4 .. t*4+3]
    const f4* p1 = (const f4*)(base + 1024 + t * 4);   // cols [1024+t*4 ..]
    f4 a0 = (f4)(0.f);
    f4 a1 = (f4)(0.f);
#pragma unroll 8
    for (int s = 0; s < S_PER; ++s) {
        f4 v0 = __builtin_nontemporal_load(p0 + (size_t)s * (HID / 4));
        f4 v1 = __builtin_nontemporal_load(p1 + (size_t)s * (HID / 4));
        a0 += v0;
        a1 += v1;
    }
    *(f4*)&hsum[t * 4]        = a0;
    *(f4*)&hsum[1024 + t * 4] = a1;
    __syncthreads();

    // project: c[j] = sum_h hsum[h] * W1[h][j]; 8 groups of 32 lanes,
    // group g owns h in [g*256, g*256+256). hsum reads are broadcast (free);
    // W1 reads are 128B-coalesced per group, L2-resident (256 KB).
    int j = t & 31, g = t >> 5;
    const float* w = W1 + (size_t)(g * 256) * AD + j;
    float c = 0.f;
#pragma unroll 4
    for (int k = 0; k < 256; ++k)
        c += hsum[g * 256 + k] * w[(size_t)k * AD];
    cpart[g][j] = c;
    __syncthreads();

    if (t < AD) {
        float s = 0.f;
#pragma unroll
        for (int gg = 0; gg < 8; ++gg) s += cpart[gg][t];
        xpart[((size_t)(b * SC + sc)) * AD + t] = s;
    }
}

// ---- Kernel 2: per-block controller redo + masked scale + Hadamard ----
// grid 256, block 128 -> one row per thread, 128 rows per block, 32 blocks
// per batch. Every block redundantly recomputes the tiny controller for its
// batch from xpart (32 KB, L2-hot) -> deterministic identical mask; then
// streams its 128 rows of rank_activations through the masked FWHT-16.
__global__ void ctrl_hadamard(const float* __restrict__ xpart,
                              const float* __restrict__ b1,
                              const float* __restrict__ gamma,
                              const float* __restrict__ beta,
                              const float* __restrict__ W2,
                              const float* __restrict__ b2v,
                              const float* __restrict__ mlog,
                              const float* __restrict__ rsc,
                              const float* __restrict__ ra,
                              float* __restrict__ out) {
    __shared__ float xp[4][AD];
    __shared__ float xv[AD];
    __shared__ float xg[AD];
    __shared__ float comb[R];
    __shared__ float ms[R];
    int t   = threadIdx.x;            // 0..127
    int blk = blockIdx.x;             // 0..255
    int b   = blk >> 5;               // 32 blocks per batch

    // --- controller (redundant per block, identical across a batch) ---
    int j = t & 31, g = t >> 5;       // 4 groups of 32
    const float* xb = xpart + (size_t)b * SC * AD;
    float s = 0.f;
#pragma unroll 8
    for (int r = 0; r < SC / 4; ++r)          // 64 rows per group
        s += xb[(size_t)(g * (SC / 4) + r) * AD + j];
    xp[g][j] = s;
    __syncthreads();

    if (t < AD) {
        float x = 0.f;
#pragma unroll
        for (int gg = 0; gg < 4; ++gg) x += xp[gg][t];
        xv[t] = x * (1.0f / (float)S_LEN) + b1[t];
    }
    __syncthreads();

    if (t < AD) {
        float mu = 0.f;
#pragma unroll
        for (int k = 0; k < AD; ++k) mu += xv[k];
        mu *= (1.0f / AD);
        float var = 0.f;
#pragma unroll
        for (int k = 0; k < AD; ++k) { float d = xv[k] - mu; var += d * d; }
        var *= (1.0f / AD);
        float x = (xv[t] - mu) * rsqrtf(var + 1e-5f) * gamma[t] + beta[t];
        xg[t] = 0.5f * x * (1.0f + erff(x * 0.70710678118654752f));  // exact GELU
    }
    __syncthreads();

    if (t < R) {
        float lg = b2v[t];
#pragma unroll
        for (int k = 0; k < AD; ++k) lg += xg[k] * W2[(size_t)k * R + t];
        comb[t] = lg + mlog[t];
    }
    __syncthreads();

    if (t < R) {
        float v = comb[t];
        int cnt = 0;
#pragma unroll
        for (int k = 0; k < R; ++k)
            cnt += (comb[k] > v) || (comb[k] == v && k < t);
        ms[t] = (cnt < 8) ? rsc[t] : 0.f;
    }
    __syncthreads();

    // --- masked scale + FWHT-16 (one row per thread) ---
    size_t row = (size_t)blk * 128 + t;
    const f4* src = (const f4*)(ra + row * R);
    float a[R];
#pragma unroll
    for (int i = 0; i < 4; ++i) {
        f4 v = __builtin_nontemporal_load(src + i);
        a[4 * i + 0] = v.x; a[4 * i + 1] = v.y;
        a[4 * i + 2] = v.z; a[4 * i + 3] = v.w;
    }
#pragma unroll
    for (int r = 0; r < R; ++r) a[r] *= ms[r];

    // FWHT-16 (Sylvester ordering); recursive /sqrt(n) => total 1/32
#pragma unroll
    for (int hstep = 1; hstep < R; hstep <<= 1) {
#pragma unroll
        for (int i = 0; i < R; ++i) {
            if ((i & hstep) == 0) {
                float u = a[i], v = a[i | hstep];
                a[i] = u + v; a[i | hstep] = u - v;
            }
        }
    }

    f4* dst = (f4*)(out + row * R);
#pragma unroll
    for (int i = 0; i < 4; ++i) {
        f4 v;
        v.x = a[4 * i + 0] * 0.03125f; v.y = a[4 * i + 1] * 0.03125f;
        v.z = a[4 * i + 2] * 0.03125f; v.w = a[4 * i + 3] * 0.03125f;
        __builtin_nontemporal_store(v, dst + i);
    }
}

extern "C" void kernel_launch(void* const* d_in, const int* in_sizes, int n_in,
                              void* d_out, int out_size, void* d_ws, size_t ws_size,
                              hipStream_t stream) {
    const float* hs    = (const float*)d_in[0];  // (8,4096,2048)
    const float* ra    = (const float*)d_in[1];  // (8,4096,16)
    const float* W1    = (const float*)d_in[2];  // (2048,32)
    const float* b1    = (const float*)d_in[3];  // (32)
    const float* gamma = (const float*)d_in[4];  // (32)
    const float* beta  = (const float*)d_in[5];  // (32)
    const float* W2    = (const float*)d_in[6];  // (32,16)
    const float* b2v   = (const float*)d_in[7];  // (16)
    const float* mlog  = (const float*)d_in[8];  // (16)
    const float* rsc   = (const float*)d_in[9];  // (16)
    float* out = (float*)d_out;

    float* xpart = (float*)d_ws;                 // 2048*32 f32 = 256 KB

    pool_proj    <<<dim3(SC, NB), 256, 0, stream>>>(hs, W1, xpart);
    ctrl_hadamard<<<256, 128, 0, stream>>>(xpart, b1, gamma, beta,
                                           W2, b2v, mlog, rsc, ra, out);
}

// Round 6
// 62.907 us; speedup vs baseline: 3.2249x; 1.0155x over previous
//
#include <hip/hip_runtime.h>
#include <hip/hip_bf16.h>
#include <math.h>

#define S_LEN   4096
#define HID     2048
#define NB      8
#define SC      128           // s-chunks: one block per 32 rows (R3 best)
#define S_PER   (S_LEN / SC)  // 32 rows per block
#define R       16            // TOTAL_RANK
#define AD      32            // ADAPT_DIM

typedef float f4 __attribute__((ext_vector_type(4)));

// ---------------- Kernel 1: fused mean-pool + W1 projection ----------------
// grid (128 sc, 8 b), block 256 -> 1024 blocks (4/CU). Each block streams 32
// full rows (256 KB) with PLAIN cached loads (hs ~fits in 256MB L3 across
// replays), reduces to a 2048-float h-sum in LDS, projects onto W1
// (L2-resident), writes a 32-float partial x row.
__global__ __launch_bounds__(256)
void pool_proj(const float* __restrict__ hs,
               const float* __restrict__ W1,
               float* __restrict__ xpart) {
    __shared__ float hsum[HID];        // 8 KB
    __shared__ float cpart[8][AD];     // 1 KB
    int t  = threadIdx.x;              // 0..255
    int sc = blockIdx.x;               // 0..127
    int b  = blockIdx.y;               // 0..7

    const float* base = hs + ((size_t)b * S_LEN + (size_t)sc * S_PER) * HID;
    const f4* p0 = (const f4*)(base + t * 4);          // cols [t*4 .. t*4+3]
    const f4* p1 = (const f4*)(base + 1024 + t * 4);   // cols [1024+t*4 ..]
    f4 a0 = (f4)(0.f);
    f4 a1 = (f4)(0.f);
#pragma unroll 8
    for (int s = 0; s < S_PER; ++s) {
        f4 v0 = p0[(size_t)s * (HID / 4)];   // cached load — keep L3-resident
        f4 v1 = p1[(size_t)s * (HID / 4)];
        a0 += v0;
        a1 += v1;
    }
    *(f4*)&hsum[t * 4]        = a0;
    *(f4*)&hsum[1024 + t * 4] = a1;
    __syncthreads();

    // project: c[j] = sum_h hsum[h] * W1[h][j]; 8 groups of 32 lanes,
    // group g owns h in [g*256, g*256+256). hsum reads broadcast (free);
    // W1 reads 128B-coalesced per group, L2-resident (256 KB).
    int j = t & 31, g = t >> 5;
    const float* w = W1 + (size_t)(g * 256) * AD + j;
    float c = 0.f;
#pragma unroll 4
    for (int k = 0; k < 256; ++k)
        c += hsum[g * 256 + k] * w[(size_t)k * AD];
    cpart[g][j] = c;
    __syncthreads();

    if (t < AD) {
        float s = 0.f;
#pragma unroll
        for (int gg = 0; gg < 8; ++gg) s += cpart[gg][t];
        xpart[((size_t)(b * SC + sc)) * AD + t] = s;
    }
}

// ---- Kernel 2: per-block controller redo + masked scale + Hadamard ----
// grid 256, block 128 -> one row per thread, 128 rows per block, 32 blocks
// per batch. Every block redundantly recomputes the tiny controller for its
// batch from xpart (16 KB, L2-hot) -> deterministic identical mask; then
// streams its 128 rows of rank_activations through the masked FWHT-16.
__global__ void ctrl_hadamard(const float* __restrict__ xpart,
                              const float* __restrict__ b1,
                              const float* __restrict__ gamma,
                              const float* __restrict__ beta,
                              const float* __restrict__ W2,
                              const float* __restrict__ b2v,
                              const float* __restrict__ mlog,
                              const float* __restrict__ rsc,
                              const float* __restrict__ ra,
                              float* __restrict__ out) {
    __shared__ float xp[4][AD];
    __shared__ float xv[AD];
    __shared__ float xg[AD];
    __shared__ float comb[R];
    __shared__ float ms[R];
    int t   = threadIdx.x;            // 0..127
    int blk = blockIdx.x;             // 0..255
    int b   = blk >> 5;               // 32 blocks per batch

    // --- controller (redundant per block, identical across a batch) ---
    int j = t & 31, g = t >> 5;       // 4 groups of 32
    const float* xb = xpart + (size_t)b * SC * AD;
    float s = 0.f;
#pragma unroll 8
    for (int r = 0; r < SC / 4; ++r)          // 32 rows per group
        s += xb[(size_t)(g * (SC / 4) + r) * AD + j];
    xp[g][j] = s;
    __syncthreads();

    if (t < AD) {
        float x = 0.f;
#pragma unroll
        for (int gg = 0; gg < 4; ++gg) x += xp[gg][t];
        xv[t] = x * (1.0f / (float)S_LEN) + b1[t];
    }
    __syncthreads();

    if (t < AD) {
        float mu = 0.f;
#pragma unroll
        for (int k = 0; k < AD; ++k) mu += xv[k];
        mu *= (1.0f / AD);
        float var = 0.f;
#pragma unroll
        for (int k = 0; k < AD; ++k) { float d = xv[k] - mu; var += d * d; }
        var *= (1.0f / AD);
        float x = (xv[t] - mu) * rsqrtf(var + 1e-5f) * gamma[t] + beta[t];
        xg[t] = 0.5f * x * (1.0f + erff(x * 0.70710678118654752f));  // exact GELU
    }
    __syncthreads();

    if (t < R) {
        float lg = b2v[t];
#pragma unroll
        for (int k = 0; k < AD; ++k) lg += xg[k] * W2[(size_t)k * R + t];
        comb[t] = lg + mlog[t];
    }
    __syncthreads();

    if (t < R) {
        float v = comb[t];
        int cnt = 0;
#pragma unroll
        for (int k = 0; k < R; ++k)
            cnt += (comb[k] > v) || (comb[k] == v && k < t);
        ms[t] = (cnt < 8) ? rsc[t] : 0.f;
    }
    __syncthreads();

    // --- masked scale + FWHT-16 (one row per thread) ---
    size_t row = (size_t)blk * 128 + t;
    const f4* src = (const f4*)(ra + row * R);
    float a[R];
#pragma unroll
    for (int i = 0; i < 4; ++i) {
        f4 v = src[i];                 // cached load (ra is 2MB, L3-resident)
        a[4 * i + 0] = v.x; a[4 * i + 1] = v.y;
        a[4 * i + 2] = v.z; a[4 * i + 3] = v.w;
    }
#pragma unroll
    for (int r = 0; r < R; ++r) a[r] *= ms[r];

    // FWHT-16 (Sylvester ordering); recursive /sqrt(n) => total 1/32
#pragma unroll
    for (int hstep = 1; hstep < R; hstep <<= 1) {
#pragma unroll
        for (int i = 0; i < R; ++i) {
            if ((i & hstep) == 0) {
                float u = a[i], v = a[i | hstep];
                a[i] = u + v; a[i | hstep] = u - v;
            }
        }
    }

    f4* dst = (f4*)(out + row * R);
#pragma unroll
    for (int i = 0; i < 4; ++i) {
        f4 v;
        v.x = a[4 * i + 0] * 0.03125f; v.y = a[4 * i + 1] * 0.03125f;
        v.z = a[4 * i + 2] * 0.03125f; v.w = a[4 * i + 3] * 0.03125f;
        __builtin_nontemporal_store(v, dst + i);   // write-only stream
    }
}

extern "C" void kernel_launch(void* const* d_in, const int* in_sizes, int n_in,
                              void* d_out, int out_size, void* d_ws, size_t ws_size,
                              hipStream_t stream) {
    const float* hs    = (const float*)d_in[0];  // (8,4096,2048)
    const float* ra    = (const float*)d_in[1];  // (8,4096,16)
    const float* W1    = (const float*)d_in[2];  // (2048,32)
    const float* b1    = (const float*)d_in[3];  // (32)
    const float* gamma = (const float*)d_in[4];  // (32)
    const float* beta  = (const float*)d_in[5];  // (32)
    const float* W2    = (const float*)d_in[6];  // (32,16)
    const float* b2v   = (const float*)d_in[7];  // (16)
    const float* mlog  = (const float*)d_in[8];  // (16)
    const float* rsc   = (const float*)d_in[9];  // (16)
    float* out = (float*)d_out;

    float* xpart = (float*)d_ws;                 // 1024*32 f32 = 128 KB

    pool_proj    <<<dim3(SC, NB), 256, 0, stream>>>(hs, W1, xpart);
    ctrl_hadamard<<<256, 128, 0, stream>>>(xpart, b1, gamma, beta,
                                           W2, b2v, mlog, rsc, ra, out);
}

// Round 7
// 60.459 us; speedup vs baseline: 3.3555x; 1.0405x over previous
//
#include <hip/hip_runtime.h>
#include <hip/hip_bf16.h>
#include <math.h>

#define S_LEN   4096
#define HID     2048
#define NB      8
#define SC      128           // s-chunks: one block per 32 rows (R3 best)
#define S_PER   (S_LEN / SC)  // 32 rows per block
#define R       16            // TOTAL_RANK
#define AD      32            // ADAPT_DIM

typedef float f4 __attribute__((ext_vector_type(4)));

// ---------------- Kernel 1: fused mean-pool + W1 projection ----------------
// (byte-identical to R3's 56.8us version: NT loads for hs, SC=128)
__global__ void pool_proj(const float* __restrict__ hs,
                          const float* __restrict__ W1,
                          float* __restrict__ xpart) {
    __shared__ float hsum[HID];        // 8 KB
    __shared__ float cpart[8][AD];     // 1 KB
    int t  = threadIdx.x;              // 0..255
    int sc = blockIdx.x;               // 0..127
    int b  = blockIdx.y;               // 0..7

    const float* base = hs + ((size_t)b * S_LEN + (size_t)sc * S_PER) * HID;
    const f4* p0 = (const f4*)(base + t * 4);          // cols [t*4 .. t*4+3]
    const f4* p1 = (const f4*)(base + 1024 + t * 4);   // cols [1024+t*4 ..]
    f4 a0 = (f4)(0.f);
    f4 a1 = (f4)(0.f);
#pragma unroll 8
    for (int s = 0; s < S_PER; ++s) {
        f4 v0 = __builtin_nontemporal_load(p0 + (size_t)s * (HID / 4));
        f4 v1 = __builtin_nontemporal_load(p1 + (size_t)s * (HID / 4));
        a0 += v0;
        a1 += v1;
    }
    *(f4*)&hsum[t * 4]        = a0;
    *(f4*)&hsum[1024 + t * 4] = a1;
    __syncthreads();

    // c[j] = sum_h hsum[h]*W1[h][j]; 8 groups of 32 lanes, W1 L2-resident
    int j = t & 31, g = t >> 5;
    const float* w = W1 + (size_t)(g * 256) * AD + j;
    float c = 0.f;
#pragma unroll 4
    for (int k = 0; k < 256; ++k)
        c += hsum[g * 256 + k] * w[(size_t)k * AD];
    cpart[g][j] = c;
    __syncthreads();

    if (t < AD) {
        float s = 0.f;
#pragma unroll
        for (int gg = 0; gg < 8; ++gg) s += cpart[gg][t];
        xpart[((size_t)(b * SC + sc)) * AD + t] = s;
    }
}

// ---- Kernel 2: barrier-free wave-redundant controller + masked FWHT ----
// grid 256 x 128 threads (2 waves/block). Each WAVE redundantly computes the
// controller for its batch entirely in registers/shuffles (no LDS, no
// __syncthreads), then each thread streams one ra row through the masked
// FWHT-16. 1/32 folded into the mask scale.
__global__ void ctrl_hadamard(const float* __restrict__ xpart,
                              const float* __restrict__ b1,
                              const float* __restrict__ gamma,
                              const float* __restrict__ beta,
                              const float* __restrict__ W2,
                              const float* __restrict__ b2v,
                              const float* __restrict__ mlog,
                              const float* __restrict__ rsc,
                              const float* __restrict__ ra,
                              float* __restrict__ out) {
    int t   = threadIdx.x;            // 0..127
    int blk = blockIdx.x;             // 0..255
    int b   = blk >> 5;               // 32 blocks per batch
    int lane = t & 63;
    int j    = lane & 31;             // adapt-dim column this lane owns
    int half = lane >> 5;             // 0 or 1

    // --- xpart reduce: half h sums rows [h*64, h*64+64) of xpart[b] ---
    const float* xb = xpart + ((size_t)b * SC + half * 64) * AD + j;
    float s = 0.f;
#pragma unroll 8
    for (int r = 0; r < 64; ++r) s += xb[(size_t)r * AD];
    s += __shfl_xor(s, 32);           // full column sum, all lanes

    float xv = s * (1.0f / (float)S_LEN) + b1[j];

    // --- LN stats: each j appears twice across 64 lanes -> sum64/64 = mean32
    float m = xv;
#pragma unroll
    for (int d = 1; d < 64; d <<= 1) m += __shfl_xor(m, d);
    float mu = m * (1.0f / 64.0f);
    float dv = xv - mu;
    float vs = dv * dv;
#pragma unroll
    for (int d = 1; d < 64; d <<= 1) vs += __shfl_xor(vs, d);
    float var = vs * (1.0f / 64.0f);

    float xln = dv * rsqrtf(var + 1e-5f) * gamma[j] + beta[j];
    float xg  = 0.5f * xln * (1.0f + erff(xln * 0.70710678118654752f)); // exact GELU

    // --- W2: half h computes logits k = h*8 + kk, kk=0..7 ---
    float p[8];
#pragma unroll
    for (int kk = 0; kk < 8; ++kk)
        p[kk] = xg * W2[(size_t)j * R + half * 8 + kk];
#pragma unroll
    for (int d = 1; d < 32; d <<= 1) {
#pragma unroll
        for (int kk = 0; kk < 8; ++kk) p[kk] += __shfl_xor(p[kk], d);
    }
#pragma unroll
    for (int kk = 0; kk < 8; ++kk)
        p[kk] += b2v[half * 8 + kk] + mlog[half * 8 + kk];

    // --- exchange halves: build comb[0..15] in every lane (static idx) ---
    float q[8];
#pragma unroll
    for (int kk = 0; kk < 8; ++kk) q[kk] = __shfl_xor(p[kk], 32);
    float lo[8], hi[8];
#pragma unroll
    for (int kk = 0; kk < 8; ++kk) {
        lo[kk] = (half == 0) ? p[kk] : q[kk];   // comb[kk]
        hi[kk] = (half == 0) ? q[kk] : p[kk];   // comb[8+kk]
    }

    // --- top-8-of-16 (first-index tie-break), fold rsc * 1/32 ---
    float msv[R];
#pragma unroll
    for (int k = 0; k < 8; ++k) {
        float v = lo[k];
        int cnt = 0;
#pragma unroll
        for (int m2 = 0; m2 < 8; ++m2) {
            cnt += (lo[m2] > v) || (lo[m2] == v && m2 < k);
            cnt += (hi[m2] > v);                 // idx 8+m2 > k always
        }
        msv[k] = (cnt < 8) ? rsc[k] * 0.03125f : 0.f;
    }
#pragma unroll
    for (int k = 0; k < 8; ++k) {
        float v = hi[k];
        int cnt = 0;
#pragma unroll
        for (int m2 = 0; m2 < 8; ++m2) {
            cnt += (lo[m2] > v) || (lo[m2] == v);            // idx m2 < 8+k always
            cnt += (hi[m2] > v) || (hi[m2] == v && m2 < k);
        }
        msv[8 + k] = (cnt < 8) ? rsc[8 + k] * 0.03125f : 0.f;
    }

    // --- one row per thread: masked scale + FWHT-16 ---
    size_t row = (size_t)blk * 128 + t;
    const f4* src = (const f4*)(ra + row * R);
    float a[R];
#pragma unroll
    for (int i = 0; i < 4; ++i) {
        f4 v = src[i];
        a[4 * i + 0] = v.x; a[4 * i + 1] = v.y;
        a[4 * i + 2] = v.z; a[4 * i + 3] = v.w;
    }
#pragma unroll
    for (int r = 0; r < R; ++r) a[r] *= msv[r];

    // FWHT-16 (Sylvester); recursive /sqrt(n) already folded (1/32 in msv)
#pragma unroll
    for (int hstep = 1; hstep < R; hstep <<= 1) {
#pragma unroll
        for (int i = 0; i < R; ++i) {
            if ((i & hstep) == 0) {
                float u = a[i], v = a[i | hstep];
                a[i] = u + v; a[i | hstep] = u - v;
            }
        }
    }

    f4* dst = (f4*)(out + row * R);
#pragma unroll
    for (int i = 0; i < 4; ++i) {
        f4 v;
        v.x = a[4 * i + 0]; v.y = a[4 * i + 1];
        v.z = a[4 * i + 2]; v.w = a[4 * i + 3];
        __builtin_nontemporal_store(v, dst + i);
    }
}

extern "C" void kernel_launch(void* const* d_in, const int* in_sizes, int n_in,
                              void* d_out, int out_size, void* d_ws, size_t ws_size,
                              hipStream_t stream) {
    const float* hs    = (const float*)d_in[0];  // (8,4096,2048)
    const float* ra    = (const float*)d_in[1];  // (8,4096,16)
    const float* W1    = (const float*)d_in[2];  // (2048,32)
    const float* b1    = (const float*)d_in[3];  // (32)
    const float* gamma = (const float*)d_in[4];  // (32)
    const float* beta  = (const float*)d_in[5];  // (32)
    const float* W2    = (const float*)d_in[6];  // (32,16)
    const float* b2v   = (const float*)d_in[7];  // (16)
    const float* mlog  = (const float*)d_in[8];  // (16)
    const float* rsc   = (const float*)d_in[9];  // (16)
    float* out = (float*)d_out;

    float* xpart = (float*)d_ws;                 // 1024*32 f32 = 128 KB

    pool_proj    <<<dim3(SC, NB), 256, 0, stream>>>(hs, W1, xpart);
    ctrl_hadamard<<<256, 128, 0, stream>>>(xpart, b1, gamma, beta,
                                           W2, b2v, mlog, rsc, ra, out);
}